// Round 1
// baseline (478.827 us; speedup 1.0000x reference)
//
#include <hip/hip_runtime.h>

// Resample2d (FlowNet2, kernel_size=1): bilinear warp of input1 by flow.
// input1: [B, C, H, W] f32, flow: [B, 2, H, W] f32, out: [B, C, H, W] f32.
// One thread per (b, y, x) pixel; weights/indices computed once, reused
// across all C channels. Tap indices clamped to border; bilinear weights
// taken from the unclamped coordinate (matches resample2d_cuda semantics).

__global__ __launch_bounds__(256) void resample2d_kernel(
    const float* __restrict__ in,    // [B, C, H, W]
    const float* __restrict__ flow,  // [B, 2, H, W]
    float* __restrict__ out,         // [B, C, H, W]
    int B, int C, int H, int W) {
  const int HW = H * W;
  const int total = B * HW;
  int idx = blockIdx.x * blockDim.x + threadIdx.x;
  if (idx >= total) return;

  const int b = idx / HW;
  const int p = idx - b * HW;      // y*W + x within the image
  const int y = p / W;
  const int x = p - y * W;

  const float* fl = flow + (size_t)b * 2 * HW;
  const float dx = fl[p];
  const float dy = fl[HW + p];

  const float xf = (float)x + dx;
  const float yf = (float)y + dy;
  const float x0f = floorf(xf);
  const float y0f = floorf(yf);
  const float a  = xf - x0f;       // frac weight in x (from unclamped coord)
  const float bb = yf - y0f;       // frac weight in y

  const int x0i = (int)x0f;
  const int y0i = (int)y0f;
  const int x0 = min(max(x0i,     0), W - 1);
  const int x1 = min(max(x0i + 1, 0), W - 1);
  const int y0 = min(max(y0i,     0), H - 1);
  const int y1 = min(max(y0i + 1, 0), H - 1);

  const float w00 = (1.0f - a) * (1.0f - bb);
  const float w01 = a          * (1.0f - bb);
  const float w10 = (1.0f - a) * bb;
  const float w11 = a          * bb;

  const int i00 = y0 * W + x0;
  const int i01 = y0 * W + x1;
  const int i10 = y1 * W + x0;
  const int i11 = y1 * W + x1;

  const float* ib = in  + (size_t)b * C * HW;
  float*       ob = out + (size_t)b * C * HW;

#pragma unroll 4
  for (int c = 0; c < C; ++c) {
    const float* ic = ib + c * HW;
    const float v = w00 * ic[i00] + w01 * ic[i01]
                  + w10 * ic[i10] + w11 * ic[i11];
    ob[c * HW + p] = v;
  }
}

extern "C" void kernel_launch(void* const* d_in, const int* in_sizes, int n_in,
                              void* d_out, int out_size, void* d_ws, size_t ws_size,
                              hipStream_t stream) {
  const float* input1 = (const float*)d_in[0];
  const float* flow   = (const float*)d_in[1];
  float* out = (float*)d_out;

  const int B = 4, C = 64, H = 384, W = 512;
  const int total = B * H * W;            // 786432 pixels
  const int block = 256;
  const int grid = (total + block - 1) / block;  // 3072 blocks

  resample2d_kernel<<<grid, block, 0, stream>>>(input1, flow, out, B, C, H, W);
}

// Round 2
// 400.793 us; speedup vs baseline: 1.1947x; 1.1947x over previous
//
#include <hip/hip_runtime.h>
#include <string.h>

// Resample2d (FlowNet2): bilinear warp of input1 [B,C,H,W] by flow [B,2,H,W].
// One thread per pixel, looping all C channels.
//  - 64x4 pixel tiles (256 thr) for in-block vertical tap-row reuse (L1).
//  - XCD-chunked block swizzle: each XCD gets a contiguous half-image so
//    vertically adjacent tiles share tap rows in the same L2.
//  - Both x-taps (x0, x0+1) fetched with ONE 8B load from a clamped pair
//    base; border clamping is folded into per-pixel weights once, so the
//    channel loop is 2 loads + 4 FMA + 1 nontemporal store.

constexpr int B = 4, C = 64, H = 384, W = 512;
constexpr int HW = H * W;
constexpr int TW = 64, TH = 4;                 // 64x4 tile, 256 threads
constexpr int BX = W / TW;                     // 8
constexpr int BY = H / TH;                     // 96
constexpr int BLOCKS_PER_IMG = BX * BY;        // 768
constexpr int NBLOCKS = B * BLOCKS_PER_IMG;    // 3072
constexpr int NXCD = 8;
constexpr int CHUNK = NBLOCKS / NXCD;          // 384 (divides exactly)

__global__ __launch_bounds__(256) void resample2d_kernel(
    const float* __restrict__ in,    // [B, C, H, W]
    const float* __restrict__ flow,  // [B, 2, H, W]
    float* __restrict__ out) {       // [B, C, H, W]
  // XCD-aware swizzle: HW round-robins consecutive blockIdx across 8 XCDs;
  // remap so each XCD owns a contiguous chunk (= half of one image).
  const int d = blockIdx.x;
  const int l = (d % NXCD) * CHUNK + d / NXCD;

  const int b  = l / BLOCKS_PER_IMG;
  const int t  = l - b * BLOCKS_PER_IMG;
  const int by = t / BX;                       // band index (rows by*4..+3)
  const int bx = t - by * BX;

  const int tx = threadIdx.x & (TW - 1);
  const int ty = threadIdx.x >> 6;
  const int x = bx * TW + tx;
  const int y = by * TH + ty;
  const int p = y * W + x;

  const float* fl = flow + (size_t)b * 2 * HW;
  const float dx = fl[p];
  const float dy = fl[HW + p];

  const float xf = (float)x + dx;
  const float yf = (float)y + dy;
  const float x0f = floorf(xf);
  const float y0f = floorf(yf);
  const float a  = xf - x0f;                   // frac weights from UNclamped
  const float bb = yf - y0f;

  const int x0i = (int)x0f;
  const int y0i = (int)y0f;
  const int x0 = min(max(x0i,     0), W - 1);
  const int x1 = min(max(x0i + 1, 0), W - 1);
  const int y0 = min(max(y0i,     0), H - 1);
  const int y1 = min(max(y0i + 1, 0), H - 1);
  const int pb = min(max(x0i, 0), W - 2);      // pair base: covers pb, pb+1

  const float w00 = (1.0f - a) * (1.0f - bb);
  const float w01 = a          * (1.0f - bb);
  const float w10 = (1.0f - a) * bb;
  const float w11 = a          * bb;

  // Fold the x-clamp selection (x0/x1 -> pair lane .x or .y) into weights.
  const float s0 = (x0 == pb) ? 1.0f : 0.0f;   // x0 comes from lane .x?
  const float s1 = (x1 == pb) ? 1.0f : 0.0f;   // x1 comes from lane .x?
  const float wA0 = w00 * s0 + w01 * s1;           // row y0, lane .x
  const float wB0 = w00 * (1.0f - s0) + w01 * (1.0f - s1); // row y0, lane .y
  const float wA1 = w10 * s0 + w11 * s1;           // row y1, lane .x
  const float wB1 = w10 * (1.0f - s0) + w11 * (1.0f - s1); // row y1, lane .y

  const int r0 = y0 * W + pb;
  const int r1 = y1 * W + pb;

  const float* ib = in  + (size_t)b * C * HW;
  float*       ob = out + (size_t)b * C * HW;

#pragma unroll 8
  for (int c = 0; c < C; ++c) {
    const float* ic = ib + (size_t)c * HW;
    float2 v0, v1;
    __builtin_memcpy(&v0, ic + r0, 8);         // taps (y0,x0) and (y0,x0+1)
    __builtin_memcpy(&v1, ic + r1, 8);         // taps (y1,x0) and (y1,x0+1)
    const float v = wA0 * v0.x + wB0 * v0.y + wA1 * v1.x + wB1 * v1.y;
    __builtin_nontemporal_store(v, ob + (size_t)c * HW + p);
  }
}

extern "C" void kernel_launch(void* const* d_in, const int* in_sizes, int n_in,
                              void* d_out, int out_size, void* d_ws, size_t ws_size,
                              hipStream_t stream) {
  const float* input1 = (const float*)d_in[0];
  const float* flow   = (const float*)d_in[1];
  float* out = (float*)d_out;
  resample2d_kernel<<<NBLOCKS, 256, 0, stream>>>(input1, flow, out);
}